// Round 19
// baseline (234.067 us; speedup 1.0000x reference)
//
#include <hip/hip_runtime.h>
#include <math.h>

#define S_LEN 512
#define D_DIM 256
#define SLICE (S_LEN * D_DIM)   // 131072

typedef _Float16 half8  __attribute__((ext_vector_type(8)));
typedef _Float16 half4v __attribute__((ext_vector_type(4)));
typedef float   floatx4 __attribute__((ext_vector_type(4)));

// ---------------------------------------------------------------------------
// WlhT[d][e] = fp16(Wl[e][d] + (e==d))     (raw + raw@Wl == raw@(I+Wl))
// ---------------------------------------------------------------------------
__global__ __launch_bounds__(256) void prep_wl(const float* __restrict__ Wl,
                                               _Float16* __restrict__ WlhT)
{
    const int d = blockIdx.x, e = threadIdx.x;
    float v = Wl[e * D_DIM + d] + (e == d ? 1.0f : 0.0f);
    WlhT[d * D_DIM + e] = (_Float16)v;
}

// ---------------------------------------------------------------------------
// fp32 -> fp16 copies of k and q (post-linres)
// ---------------------------------------------------------------------------
__global__ __launch_bounds__(256) void cvt_fp16(const float* __restrict__ kf,
                                                const float* __restrict__ qf,
                                                _Float16* __restrict__ kh,
                                                _Float16* __restrict__ qh)
{
    const int i = (blockIdx.x * 256 + threadIdx.x) * 4;
    float4 a = *(const float4*)(kf + i);
    float4 b = *(const float4*)(qf + i);
    half4v ah = { (_Float16)a.x, (_Float16)a.y, (_Float16)a.z, (_Float16)a.w };
    half4v bh = { (_Float16)b.x, (_Float16)b.y, (_Float16)b.z, (_Float16)b.w };
    *(half4v*)(kh + i) = ah;
    *(half4v*)(qh + i) = bh;
}

// ---------------------------------------------------------------------------
// y = x + x@W + b  for [512,256]@[256,256]; 4 rows per block (fp32, small).
// ---------------------------------------------------------------------------
__global__ __launch_bounds__(256) void linres3(
    const float* __restrict__ xk, const float* __restrict__ Wk,
    const float* __restrict__ bk, float* __restrict__ yk,
    const float* __restrict__ xq, const float* __restrict__ Wq,
    const float* __restrict__ bq, float* __restrict__ yq,
    const float* __restrict__ xv, const float* __restrict__ Wv,
    const float* __restrict__ bv, float* __restrict__ yv)
{
    __shared__ float xs[4][D_DIM];
    const int r0 = blockIdx.x * 4;
    const int sel = blockIdx.y;
    const float* x = sel == 0 ? xk : (sel == 1 ? xq : xv);
    const float* W = sel == 0 ? Wk : (sel == 1 ? Wq : Wv);
    const float* b = sel == 0 ? bk : (sel == 1 ? bq : bv);
    float*       y = sel == 0 ? yk : (sel == 1 ? yq : yv);

    const int tid = threadIdx.x;
    #pragma unroll
    for (int t = 0; t < 4; ++t) xs[t][tid] = x[(r0 + t) * D_DIM + tid];
    __syncthreads();
    const float bv_ = b[tid];
    float acc[4];
    #pragma unroll
    for (int i = 0; i < 4; ++i) acc[i] = xs[i][tid] + bv_;
    #pragma unroll 4
    for (int e = 0; e < D_DIM; ++e) {
        const float w = W[e * D_DIM + tid];
        #pragma unroll
        for (int i = 0; i < 4; ++i) acc[i] += xs[i][e] * w;
    }
    #pragma unroll
    for (int i = 0; i < 4; ++i) y[(r0 + i) * D_DIM + tid] = acc[i];
}

// ---------------------------------------------------------------------------
// Final linear with partial-sum fusion: x = sum_c po[c]; out = x + x@W + b
// ---------------------------------------------------------------------------
__global__ __launch_bounds__(256) void linres_sum(
    const float* __restrict__ po, const float* __restrict__ W,
    const float* __restrict__ b, float* __restrict__ y)
{
    __shared__ float xs[4][D_DIM];
    const int tid = threadIdx.x;
    const int r0  = blockIdx.x * 4;
    #pragma unroll
    for (int t = 0; t < 4; ++t) {
        float s = 0.f;
        #pragma unroll
        for (int c = 0; c < 16; ++c)
            s += po[(size_t)c * SLICE + (r0 + t) * D_DIM + tid];
        xs[t][tid] = s;
    }
    __syncthreads();
    const float bv_ = b[tid];
    float acc[4];
    #pragma unroll
    for (int i = 0; i < 4; ++i) acc[i] = xs[i][tid] + bv_;
    #pragma unroll 4
    for (int e = 0; e < D_DIM; ++e) {
        const float w = W[e * D_DIM + tid];
        #pragma unroll
        for (int i = 0; i < 4; ++i) acc[i] += xs[i][e] * w;
    }
    #pragma unroll
    for (int i = 0; i < 4; ++i) y[(r0 + i) * D_DIM + tid] = acc[i];
}

// ---------------------------------------------------------------------------
// Stats: per-(sk,d) tile-partial (max, sum |L| e^(L-max)) over 64 sq rows.
// NO LDS: A-fragments (sk-invariant) in VGPRs, loaded once from L2.
// amdgpu_waves_per_eu(2,2): pin the allocator to the 2-waves/EU the 512-block
// grid actually delivers — R18's VGPR_Count=100 proved the allocator chased
// 5-wave occupancy we never launch, rematerializing af/wl from L2 in-loop.
// Wave tile sq64 x d16 (mt=4, nt=1); grid (8,4,16) = 512 = 2 blocks/CU.
// kk loops FULLY unrolled (dynamic indexing demotes arrays — R7-R9 bug).
// ---------------------------------------------------------------------------
__global__ __attribute__((amdgpu_flat_work_group_size(256, 256),
                          amdgpu_waves_per_eu(2, 2)))
void stats_mfma(
    const _Float16* __restrict__ qh, const _Float16* __restrict__ kh,
    const _Float16* __restrict__ WlhT, const float* __restrict__ bl,
    float* __restrict__ pm, float* __restrict__ ps)
{
    const int tid  = threadIdx.x;
    const int lane = tid & 63, wave = tid >> 6;
    const int quad = lane >> 4, l16 = lane & 15;
    const int sqt  = blockIdx.x, sq0 = sqt * 64;
    const int dw   = blockIdx.y * 64 + wave * 16;
    const int sk0  = blockIdx.z * 32;
    const int d    = dw + l16;

    half8 af[4][8];
    #pragma unroll
    for (int mt = 0; mt < 4; ++mt)
        #pragma unroll
        for (int kk = 0; kk < 8; ++kk)
            af[mt][kk] = *(const half8*)(qh +
                (size_t)(sq0 + mt * 16 + l16) * D_DIM + kk * 32 + quad * 8);

    half8 wl[8];
    #pragma unroll
    for (int kk = 0; kk < 8; ++kk)
        wl[kk] = *(const half8*)(WlhT + (size_t)d * D_DIM + kk * 32 + quad * 8);
    const float bl_r = bl[d];

    #pragma unroll 1
    for (int s = 0; s < 32; ++s) {
        const int sk = sk0 + s;
        floatx4 acc[4];
        #pragma unroll
        for (int mt = 0; mt < 4; ++mt)
            acc[mt] = (floatx4){0.f, 0.f, 0.f, 0.f};

        #pragma unroll
        for (int kk = 0; kk < 8; ++kk) {
            const half8 k8 = *(const half8*)(kh + (size_t)sk * D_DIM + kk * 32 + quad * 8);
            const half8 bf = wl[kk] * k8;
            #pragma unroll
            for (int mt = 0; mt < 4; ++mt)
                acc[mt] = __builtin_amdgcn_mfma_f32_16x16x32_f16(
                    af[mt][kk], bf, acc[mt], 0, 0, 0);
        }

        float tmax = -1e30f;
        #pragma unroll
        for (int mt = 0; mt < 4; ++mt)
            #pragma unroll
            for (int r = 0; r < 4; ++r)
                tmax = fmaxf(tmax, acc[mt][r] + bl_r);
        float tsum = 0.f;
        #pragma unroll
        for (int mt = 0; mt < 4; ++mt)
            #pragma unroll
            for (int r = 0; r < 4; ++r) {
                const float L = acc[mt][r] + bl_r;
                tsum += fabsf(L) * __expf(L - tmax);
            }

        float m = tmax, ss = tsum;
        #pragma unroll
        for (int mask = 16; mask <= 32; mask <<= 1) {
            float m2 = __shfl_xor(m, mask, 64);
            float s2 = __shfl_xor(ss, mask, 64);
            float M  = fmaxf(m, m2);
            ss = ss * __expf(m - M) + s2 * __expf(m2 - M);
            m = M;
        }
        if (quad == 0) {
            pm[((size_t)sqt * S_LEN + sk) * D_DIM + d] = m;
            ps[((size_t)sqt * S_LEN + sk) * D_DIM + d] = ss;
        }
    }
}

// ---------------------------------------------------------------------------
// Merge the 8 sq-slab partials; fold epilogue constants (R17-validated):
// msv[sk,d] = { bl - m,  v/(S+1) }
// ---------------------------------------------------------------------------
__global__ __launch_bounds__(256) void reduce_ms(
    const float* __restrict__ pm, const float* __restrict__ ps,
    const float* __restrict__ vbuf, const float* __restrict__ bl,
    float2* __restrict__ msv)
{
    const int idx = blockIdx.x * 256 + threadIdx.x;   // sk*256 + d
    float m = pm[idx], ss = ps[idx];
    #pragma unroll
    for (int t = 1; t < 8; ++t) {
        const float m2 = pm[t * SLICE + idx];
        const float s2 = ps[t * SLICE + idx];
        const float M  = fmaxf(m, m2);
        ss = ss * __expf(m - M) + s2 * __expf(m2 - M);
        m = M;
    }
    msv[idx] = make_float2(bl[idx & 255] - m, vbuf[idx] / (ss + 1.0f));
}

// ---------------------------------------------------------------------------
// Accum: recompute L', o += (L'+bl)*c.y * e^(L'+c.x) over 32 sk; plain
// stores to po[chunk] (no atomics). NO LDS; af/wl resident in VGPRs
// (amdgpu_waves_per_eu(2,2) pins the budget — see stats_mfma comment).
// R12 tile (mt=2, nt=2). Grid (16,2,16) = 512 = 2 blocks/CU.
// ---------------------------------------------------------------------------
__global__ __attribute__((amdgpu_flat_work_group_size(256, 256),
                          amdgpu_waves_per_eu(2, 2)))
void accum_mfma(
    const _Float16* __restrict__ qh, const _Float16* __restrict__ kh,
    const _Float16* __restrict__ WlhT, const float* __restrict__ bl,
    const float2* __restrict__ msv, float* __restrict__ po)
{
    const int tid  = threadIdx.x;
    const int lane = tid & 63, wave = tid >> 6;
    const int quad = lane >> 4, l16 = lane & 15;
    const int sq0  = blockIdx.x * 32;
    const int dw   = blockIdx.y * 128 + wave * 32;
    const int chunk = blockIdx.z;
    const int sk0  = chunk * 32;

    half8 af[2][8];
    #pragma unroll
    for (int mt = 0; mt < 2; ++mt)
        #pragma unroll
        for (int kk = 0; kk < 8; ++kk)
            af[mt][kk] = *(const half8*)(qh +
                (size_t)(sq0 + mt * 16 + l16) * D_DIM + kk * 32 + quad * 8);

    half8 wl[2][8];
    #pragma unroll
    for (int nt = 0; nt < 2; ++nt) {
        const int d = dw + nt * 16 + l16;
        #pragma unroll
        for (int kk = 0; kk < 8; ++kk)
            wl[nt][kk] = *(const half8*)(WlhT + (size_t)d * D_DIM + kk * 32 + quad * 8);
    }
    float bl_r[2];
    #pragma unroll
    for (int nt = 0; nt < 2; ++nt)
        bl_r[nt] = bl[dw + nt * 16 + l16];

    floatx4 o[2][2];
    #pragma unroll
    for (int mt = 0; mt < 2; ++mt)
        #pragma unroll
        for (int nt = 0; nt < 2; ++nt)
            o[mt][nt] = (floatx4){0.f, 0.f, 0.f, 0.f};

    #pragma unroll 1
    for (int s = 0; s < 32; ++s) {
        const int sk = sk0 + s;
        floatx4 acc[2][2];
        #pragma unroll
        for (int mt = 0; mt < 2; ++mt)
            #pragma unroll
            for (int nt = 0; nt < 2; ++nt)
                acc[mt][nt] = (floatx4){0.f, 0.f, 0.f, 0.f};

        #pragma unroll
        for (int kk = 0; kk < 8; ++kk) {
            const half8 k8 = *(const half8*)(kh + (size_t)sk * D_DIM + kk * 32 + quad * 8);
            half8 bf[2];
            #pragma unroll
            for (int nt = 0; nt < 2; ++nt)
                bf[nt] = wl[nt][kk] * k8;
            #pragma unroll
            for (int mt = 0; mt < 2; ++mt)
                #pragma unroll
                for (int nt = 0; nt < 2; ++nt)
                    acc[mt][nt] = __builtin_amdgcn_mfma_f32_16x16x32_f16(
                        af[mt][kk], bf[nt], acc[mt][nt], 0, 0, 0);
        }

        #pragma unroll
        for (int nt = 0; nt < 2; ++nt) {
            const float2 c = msv[((size_t)sk << 8) + dw + nt * 16 + l16];
            #pragma unroll
            for (int mt = 0; mt < 2; ++mt)
                #pragma unroll
                for (int r = 0; r < 4; ++r) {
                    const float Lp = acc[mt][nt][r];
                    const float e  = __expf(Lp + c.x);       // e^(L-m)
                    const float u  = (Lp + bl_r[nt]) * c.y;  // L * v/(S+1)
                    o[mt][nt][r] = fmaf(u, e, o[mt][nt][r]);
                }
        }
    }

    float* dst = po + (size_t)chunk * SLICE;
    #pragma unroll
    for (int mt = 0; mt < 2; ++mt)
        #pragma unroll
        for (int nt = 0; nt < 2; ++nt)
            #pragma unroll
            for (int r = 0; r < 4; ++r) {
                const int row = sq0 + mt * 16 + quad * 4 + r;
                const int col = dw + nt * 16 + l16;
                dst[(size_t)row * D_DIM + col] = o[mt][nt][r];
            }
}

// ---------------------------------------------------------------------------
extern "C" void kernel_launch(void* const* d_in, const int* in_sizes, int n_in,
                              void* d_out, int out_size, void* d_ws, size_t ws_size,
                              hipStream_t stream)
{
    const float* query = (const float*)d_in[0];
    const float* key   = (const float*)d_in[1];
    const float* value = (const float*)d_in[2];
    const float* Wk  = (const float*)d_in[3];
    const float* bk  = (const float*)d_in[4];
    const float* Wq  = (const float*)d_in[5];
    const float* bq  = (const float*)d_in[6];
    const float* Wva = (const float*)d_in[7];
    const float* bva = (const float*)d_in[8];
    const float* Wl  = (const float*)d_in[9];
    const float* bl  = (const float*)d_in[10];
    const float* Wvo = (const float*)d_in[11];
    const float* bvo = (const float*)d_in[12];

    const int MAT = SLICE;                    // 131072
    float* ws   = (float*)d_ws;
    // R12/R17/R18-proven footprint. msv in old mbuf slot; po overlays pm+ps.
    float* kbuf = ws;
    float* qbuf = ws + MAT;
    float* vbuf = ws + 2 * MAT;
    float2* msv = (float2*)(ws + 3 * MAT);                 // SLICE float2
    _Float16* WlhT = (_Float16*)(ws + 6 * MAT);            // 128 KB
    _Float16* kh   = (_Float16*)(ws + 6 * MAT + 32768);    // 256 KB
    _Float16* qh   = kh + MAT;                             // 256 KB
    float* pm  = ws + 6 * MAT + 32768 + 2 * 65536;         // 4 MB
    float* ps  = pm + 8 * MAT;                             // 4 MB
    float* po  = pm;   // 16*MAT floats (8 MB), pm/ps dead after reduce_ms
    float* out = (float*)d_out;

    prep_wl<<<256, 256, 0, stream>>>(Wl, WlhT);
    linres3<<<dim3(128, 3), 256, 0, stream>>>(key, Wk, bk, kbuf,
                                              query, Wq, bq, qbuf,
                                              value, Wva, bva, vbuf);
    cvt_fp16<<<128, 256, 0, stream>>>(kbuf, qbuf, kh, qh);

    stats_mfma<<<dim3(8, 4, 16), 256, 0, stream>>>(qh, kh, WlhT, bl, pm, ps);
    reduce_ms<<<512, 256, 0, stream>>>(pm, ps, vbuf, bl, msv);
    accum_mfma<<<dim3(16, 2, 16), 256, 0, stream>>>(qh, kh, WlhT, bl, msv, po);

    linres_sum<<<128, 256, 0, stream>>>(po, Wvo, bvo, out);
}